// Round 1
// baseline (871.304 us; speedup 1.0000x reference)
//
#include <hip/hip_runtime.h>
#include <math.h>

#define DIM 64
#define NW 4            // waves per block
#define NPB 4           // nodes per wave per iteration
#define CAP 64          // per-row edge bucket capacity (mean degree = 25)
#define OVCAP 65536     // overflow list capacity

__device__ __forceinline__ float waveReduceSum(float v) {
    #pragma unroll
    for (int off = 1; off < 64; off <<= 1)
        v += __shfl_xor(v, off, 64);
    return v;
}

// ---------------- Kernel A: LayerNorm + QKV projection ----------------
__global__ __launch_bounds__(256) void qkv_kernel(
    const float* __restrict__ node_feat,
    const float* __restrict__ ln_g, const float* __restrict__ ln_b,
    const float* __restrict__ qkv_w, const float* __restrict__ qkv_b,
    float* __restrict__ q, float* __restrict__ k, float* __restrict__ v,
    int N)
{
    __shared__ float  wlds[64 * 192];        // [d][j_permuted]  48 KB
    __shared__ float4 xs[NW][NPB][16];       // per-wave x rows   4 KB
    const int wave = threadIdx.x >> 6, lane = threadIdx.x & 63;

    for (int idx = threadIdx.x; idx < 64 * 192; idx += 256) {
        int d = idx / 192, j = idx - d * 192;
        int jj = j & 63, sec = j >> 6;                 // sec: 0=q 1=k 2=v
        int c = 12 * (jj >> 2) + (jj & 3) + 4 * sec;   // h*12 + t + 4*sec
        wlds[idx] = qkv_w[d * 192 + c];
    }
    const int c0 = 12 * (lane >> 2) + (lane & 3);
    const float b0 = qkv_b[c0], b1 = qkv_b[c0 + 4], b2 = qkv_b[c0 + 8];
    const float gg = ln_g[lane], bb = ln_b[lane];
    __syncthreads();

    const int nstride = gridDim.x * NW * NPB;
    for (int n0 = (blockIdx.x * NW + wave) * NPB; n0 < N; n0 += nstride) {
        const int cnt = min(NPB, N - n0);
        float acc0[NPB], acc1[NPB], acc2[NPB];
        #pragma unroll
        for (int i = 0; i < NPB; ++i) {
            acc0[i] = b0; acc1[i] = b1; acc2[i] = b2;
            if (i < cnt) {
                float nf = node_feat[(size_t)(n0 + i) * DIM + lane];
                float mu = waveReduceSum(nf) * (1.0f / 64.0f);
                float dv = nf - mu;
                float var = waveReduceSum(dv * dv) * (1.0f / 64.0f);
                float x = dv * rsqrtf(var + 1e-5f) * gg + bb;
                ((float*)&xs[wave][i][0])[lane] = x;
            }
        }
        #pragma unroll 4
        for (int d4 = 0; d4 < 16; ++d4) {
            float4 xv[NPB];
            #pragma unroll
            for (int i = 0; i < NPB; ++i) xv[i] = xs[wave][i][d4];
            #pragma unroll
            for (int u = 0; u < 4; ++u) {
                int d = d4 * 4 + u;
                float w0 = wlds[d * 192 + lane];
                float w1 = wlds[d * 192 + lane + 64];
                float w2 = wlds[d * 192 + lane + 128];
                #pragma unroll
                for (int i = 0; i < NPB; ++i) {
                    float xd = (&xv[i].x)[u];
                    acc0[i] = fmaf(xd, w0, acc0[i]);
                    acc1[i] = fmaf(xd, w1, acc1[i]);
                    acc2[i] = fmaf(xd, w2, acc2[i]);
                }
            }
        }
        #pragma unroll
        for (int i = 0; i < NPB; ++i) if (i < cnt) {
            size_t off = (size_t)(n0 + i) * DIM + lane;
            q[off] = acc0[i]; k[off] = acc1[i]; v[off] = acc2[i];
        }
    }
}

// ---------------- Kernel B: input_dot (+ zero m_agg, deg, ovcnt) ----------------
__global__ __launch_bounds__(256) void vec_kernel(
    const float* __restrict__ node_vec,
    const float* __restrict__ vec_w,
    float* __restrict__ input_dot,
    float* __restrict__ m_agg,
    int* __restrict__ deg,
    int* __restrict__ ovcnt,
    int N)
{
    __shared__ float  vlds[64 * 128];          // 32 KB
    __shared__ float4 nvs[NW][NPB][3][16];     // 12 KB
    const int wave = threadIdx.x >> 6, lane = threadIdx.x & 63;

    if (blockIdx.x == 0 && threadIdx.x == 0) *ovcnt = 0;

    for (int idx = threadIdx.x; idx < 64 * 128; idx += 256)
        vlds[idx] = vec_w[idx];
    __syncthreads();

    const int nstride = gridDim.x * NW * NPB;
    for (int n0 = (blockIdx.x * NW + wave) * NPB; n0 < N; n0 += nstride) {
        const int cnt = min(NPB, N - n0);
        float a0[NPB][3], a1[NPB][3];
        #pragma unroll
        for (int i = 0; i < NPB; ++i) {
            #pragma unroll
            for (int s = 0; s < 3; ++s) {
                a0[i][s] = 0.f; a1[i][s] = 0.f;
                if (i < cnt)
                    ((float*)&nvs[wave][i][s][0])[lane] =
                        node_vec[((size_t)(n0 + i) * 3 + s) * DIM + lane];
            }
        }
        #pragma unroll 2
        for (int d4 = 0; d4 < 16; ++d4) {
            #pragma unroll
            for (int u = 0; u < 4; ++u) {
                int d = d4 * 4 + u;
                float w0 = vlds[d * 128 + lane];
                float w1 = vlds[d * 128 + lane + 64];
                #pragma unroll
                for (int i = 0; i < NPB; ++i) {
                    #pragma unroll
                    for (int s = 0; s < 3; ++s) {
                        float nv = ((float*)&nvs[wave][i][s][d4])[u];
                        a0[i][s] = fmaf(nv, w0, a0[i][s]);
                        a1[i][s] = fmaf(nv, w1, a1[i][s]);
                    }
                }
            }
        }
        #pragma unroll
        for (int i = 0; i < NPB; ++i) if (i < cnt) {
            size_t off = (size_t)(n0 + i) * DIM + lane;
            input_dot[off] = a0[i][0] * a1[i][0] + a0[i][1] * a1[i][1]
                           + a0[i][2] * a1[i][2];
            m_agg[off] = 0.0f;
            if (lane == 0) deg[n0 + i] = 0;
        }
    }
}

// ---------------- Kernel S: bucket edges by destination row ----------------
// 1.25M int atomics (histogram+slot) replace 80M float atomic RMWs.
__global__ __launch_bounds__(256) void scatter_kernel(
    const int* __restrict__ row,
    const int* __restrict__ col,
    int* __restrict__ deg,
    int* __restrict__ perm,
    int* __restrict__ ovcnt,
    int* __restrict__ ovlist,
    const float* __restrict__ q, const float* __restrict__ k,
    const float* __restrict__ v,
    const float* __restrict__ edge_feat, const float* __restrict__ radial,
    float* __restrict__ m_agg,
    int E)
{
    for (int e = blockIdx.x * 256 + threadIdx.x; e < E; e += gridDim.x * 256) {
        int r = row[e];
        int slot = atomicAdd(&deg[r], 1);
        if (slot < CAP) {
            perm[(size_t)r * CAP + slot] = e;
        } else {
            int o = atomicAdd(ovcnt, 1);
            if (o < OVCAP) {
                ovlist[o] = e;
            } else {
                // astronomically rare full fallback: scalar per-edge update
                int c = col[e];
                float rad = radial[e];
                float ah[16];
                #pragma unroll
                for (int h = 0; h < 16; ++h) {
                    float p = 0.f;
                    #pragma unroll
                    for (int t = 0; t < 4; ++t)
                        p += q[(size_t)r * DIM + h * 4 + t] *
                             k[(size_t)c * DIM + h * 4 + t];
                    float g = 0.5f * p * (1.0f + erff(p * 0.70710678118654752f));
                    ah[h] = g * rad;
                }
                for (int d = 0; d < DIM; ++d)
                    atomicAdd(&m_agg[(size_t)r * DIM + d],
                              v[(size_t)c * DIM + d] *
                              edge_feat[(size_t)e * DIM + d] * ah[d >> 2]);
            }
        }
    }
}

// ---------------- Kernel C: per-row register aggregation (no atomics) ----------
__global__ __launch_bounds__(256) void agg_kernel(
    const float* __restrict__ q,
    const float* __restrict__ k,
    const float* __restrict__ v,
    const float* __restrict__ edge_feat, // (E,64)
    const float* __restrict__ radial,
    const int* __restrict__ col,
    const int* __restrict__ perm,
    const int* __restrict__ deg,
    float* __restrict__ m_agg,
    int N)
{
    const int wave = threadIdx.x >> 6, lane = threadIdx.x & 63;
    for (int n = blockIdx.x * NW + wave; n < N; n += gridDim.x * NW) {
        int cn = min(deg[n], CAP);
        const int* pr = perm + (size_t)n * CAP;
        const float qd = q[n * DIM + lane];
        float acc = 0.0f;
        #pragma unroll 2
        for (int j = 0; j < cn; ++j) {
            int e = pr[j];
            int c = col[e];
            float kd = k[c * DIM + lane];
            float vd = v[c * DIM + lane];
            // edge_feat streams once (320 MB): NT keeps it out of L2 so the
            // q/k/v gather set stays cache-resident
            float ef = __builtin_nontemporal_load(&edge_feat[e * DIM + lane]);
            float rad = radial[e];
            float p = qd * kd;
            p += __shfl_xor(p, 1, 64);
            p += __shfl_xor(p, 2, 64);   // per-head dot in all 4 lanes
            float g = 0.5f * p * (1.0f + erff(p * 0.70710678118654752f));
            acc = fmaf(vd * ef, g * rad, acc);
        }
        // += picks up rare scatter-time fallback contributions (m_agg pre-zeroed)
        m_agg[n * DIM + lane] += acc;
    }
}

// ---------------- Kernel O: overflow edges (normally empty) ----------------
__global__ __launch_bounds__(256) void ovf_kernel(
    const float* __restrict__ q,
    const float* __restrict__ k,
    const float* __restrict__ v,
    const float* __restrict__ edge_feat,
    const float* __restrict__ radial,
    const int* __restrict__ row,
    const int* __restrict__ col,
    const int* __restrict__ ovcnt,
    const int* __restrict__ ovlist,
    float* __restrict__ m_agg)
{
    const int wave = threadIdx.x >> 6, lane = threadIdx.x & 63;
    const int ovn = min(*ovcnt, OVCAP);
    for (int i = blockIdx.x * NW + wave; i < ovn; i += gridDim.x * NW) {
        int e = ovlist[i];
        int r = row[e], c = col[e];
        float p = q[r * DIM + lane] * k[c * DIM + lane];
        p += __shfl_xor(p, 1, 64);
        p += __shfl_xor(p, 2, 64);
        float g = 0.5f * p * (1.0f + erff(p * 0.70710678118654752f));
        float a = g * radial[e];
        float m = v[c * DIM + lane] * edge_feat[(size_t)e * DIM + lane] * a;
        atomicAdd(&m_agg[r * DIM + lane], m);
    }
}

// ---------------- Kernel D: output projection + epilogue ----------------
__global__ __launch_bounds__(256) void out_kernel(
    const float* __restrict__ m_agg,
    const float* __restrict__ input_dot,
    const float* __restrict__ out_w,   // (64,128)
    const float* __restrict__ out_b,   // (128,)
    float* __restrict__ result,        // (N,64)
    int N)
{
    __shared__ float  olds[64 * 128];      // 32 KB
    __shared__ float4 ms[NW][NPB][16];     // 4 KB
    const int wave = threadIdx.x >> 6, lane = threadIdx.x & 63;

    for (int idx = threadIdx.x; idx < 64 * 128; idx += 256)
        olds[idx] = out_w[idx];
    const float ob0 = out_b[lane], ob1 = out_b[lane + 64];
    __syncthreads();

    const int nstride = gridDim.x * NW * NPB;
    for (int n0 = (blockIdx.x * NW + wave) * NPB; n0 < N; n0 += nstride) {
        const int cnt = min(NPB, N - n0);
        float o0[NPB], o1[NPB];
        #pragma unroll
        for (int i = 0; i < NPB; ++i) {
            o0[i] = ob0; o1[i] = ob1;
            if (i < cnt)
                ((float*)&ms[wave][i][0])[lane] =
                    m_agg[(size_t)(n0 + i) * DIM + lane];
        }
        #pragma unroll 4
        for (int d4 = 0; d4 < 16; ++d4) {
            float4 mv[NPB];
            #pragma unroll
            for (int i = 0; i < NPB; ++i) mv[i] = ms[wave][i][d4];
            #pragma unroll
            for (int u = 0; u < 4; ++u) {
                int d = d4 * 4 + u;
                float w0 = olds[d * 128 + lane];
                float w1 = olds[d * 128 + lane + 64];
                #pragma unroll
                for (int i = 0; i < NPB; ++i) {
                    float md = (&mv[i].x)[u];
                    o0[i] = fmaf(md, w0, o0[i]);
                    o1[i] = fmaf(md, w1, o1[i]);
                }
            }
        }
        #pragma unroll
        for (int i = 0; i < NPB; ++i) if (i < cnt) {
            size_t off = (size_t)(n0 + i) * DIM + lane;
            result[off] = input_dot[off] * o0[i] + o1[i];
        }
    }
}

extern "C" void kernel_launch(void* const* d_in, const int* in_sizes, int n_in,
                              void* d_out, int out_size, void* d_ws, size_t ws_size,
                              hipStream_t stream)
{
    const float* node_feat = (const float*)d_in[0];
    const float* edge_feat = (const float*)d_in[1];
    const float* node_vec  = (const float*)d_in[2];
    const float* radial    = (const float*)d_in[3];
    const float* ln_g      = (const float*)d_in[4];
    const float* ln_b      = (const float*)d_in[5];
    const float* qkv_w     = (const float*)d_in[6];
    const float* qkv_b     = (const float*)d_in[7];
    const float* vec_w     = (const float*)d_in[8];
    const float* out_w     = (const float*)d_in[9];
    const float* out_b     = (const float*)d_in[10];
    const int*   row       = (const int*)d_in[11];
    const int*   col       = (const int*)d_in[12];

    const int N = in_sizes[0] / DIM;   // 50000
    const int E = in_sizes[3];         // 1250000

    float* ws    = (float*)d_ws;
    float* q     = ws;
    float* k     = q    + (size_t)N * DIM;
    float* v     = k    + (size_t)N * DIM;
    float* idot  = v    + (size_t)N * DIM;
    float* m_agg = idot + (size_t)N * DIM;
    int*   deg    = (int*)(m_agg + (size_t)N * DIM);
    int*   ovcnt  = deg + N;
    int*   ovlist = ovcnt + 1;
    int*   perm   = ovlist + OVCAP;    // N*CAP ints = 12.8 MB

    const int grid_nodes = 768;
    const int grid_agg   = (N + NW - 1) / NW;   // one wave per row

    qkv_kernel<<<grid_nodes, 256, 0, stream>>>(node_feat, ln_g, ln_b,
                                               qkv_w, qkv_b, q, k, v, N);
    vec_kernel<<<grid_nodes, 256, 0, stream>>>(node_vec, vec_w, idot, m_agg,
                                               deg, ovcnt, N);
    scatter_kernel<<<2048, 256, 0, stream>>>(row, col, deg, perm, ovcnt, ovlist,
                                             q, k, v, edge_feat, radial, m_agg, E);
    agg_kernel<<<grid_agg, 256, 0, stream>>>(q, k, v, edge_feat, radial,
                                             col, perm, deg, m_agg, N);
    ovf_kernel<<<256, 256, 0, stream>>>(q, k, v, edge_feat, radial,
                                        row, col, ovcnt, ovlist, m_agg);
    out_kernel<<<grid_nodes, 256, 0, stream>>>(m_agg, idot, out_w, out_b,
                                               (float*)d_out, N);
}

// Round 2
// 734.099 us; speedup vs baseline: 1.1869x; 1.1869x over previous
//
#include <hip/hip_runtime.h>
#include <math.h>

#define DIM 64
#define NW 4            // waves per block
#define NPB 4           // nodes per wave per iteration
#define CAP 64          // per-row edge bucket capacity (mean degree = 25)

__device__ __forceinline__ float waveReduceSum(float v) {
    #pragma unroll
    for (int off = 1; off < 64; off <<= 1)
        v += __shfl_xor(v, off, 64);
    return v;
}

// ---------------- Kernel A: LayerNorm + QKV projection (+ zero deg/ovcnt) ----
__global__ __launch_bounds__(256) void qkv_kernel(
    const float* __restrict__ node_feat,
    const float* __restrict__ ln_g, const float* __restrict__ ln_b,
    const float* __restrict__ qkv_w, const float* __restrict__ qkv_b,
    float* __restrict__ q, float* __restrict__ k, float* __restrict__ v,
    int* __restrict__ deg, int* __restrict__ ovcnt,
    int N)
{
    __shared__ float  wlds[64 * 192];        // [d][j_permuted]  48 KB
    __shared__ float4 xs[NW][NPB][16];       // per-wave x rows   4 KB
    const int wave = threadIdx.x >> 6, lane = threadIdx.x & 63;

    // zero bucket counters for the scatter phase (runs in the NEXT kernel)
    for (int i = blockIdx.x * 256 + threadIdx.x; i < N; i += gridDim.x * 256)
        deg[i] = 0;
    if (blockIdx.x == 0 && threadIdx.x == 0) *ovcnt = 0;

    for (int idx = threadIdx.x; idx < 64 * 192; idx += 256) {
        int d = idx / 192, j = idx - d * 192;
        int jj = j & 63, sec = j >> 6;                 // sec: 0=q 1=k 2=v
        int c = 12 * (jj >> 2) + (jj & 3) + 4 * sec;   // h*12 + t + 4*sec
        wlds[idx] = qkv_w[d * 192 + c];
    }
    const int c0 = 12 * (lane >> 2) + (lane & 3);
    const float b0 = qkv_b[c0], b1 = qkv_b[c0 + 4], b2 = qkv_b[c0 + 8];
    const float gg = ln_g[lane], bb = ln_b[lane];
    __syncthreads();

    const int nstride = gridDim.x * NW * NPB;
    for (int n0 = (blockIdx.x * NW + wave) * NPB; n0 < N; n0 += nstride) {
        const int cnt = min(NPB, N - n0);
        float acc0[NPB], acc1[NPB], acc2[NPB];
        #pragma unroll
        for (int i = 0; i < NPB; ++i) {
            acc0[i] = b0; acc1[i] = b1; acc2[i] = b2;
            if (i < cnt) {
                float nf = node_feat[(size_t)(n0 + i) * DIM + lane];
                float mu = waveReduceSum(nf) * (1.0f / 64.0f);
                float dv = nf - mu;
                float var = waveReduceSum(dv * dv) * (1.0f / 64.0f);
                float x = dv * rsqrtf(var + 1e-5f) * gg + bb;
                ((float*)&xs[wave][i][0])[lane] = x;
            }
        }
        #pragma unroll 4
        for (int d4 = 0; d4 < 16; ++d4) {
            float4 xv[NPB];
            #pragma unroll
            for (int i = 0; i < NPB; ++i) xv[i] = xs[wave][i][d4];
            #pragma unroll
            for (int u = 0; u < 4; ++u) {
                int d = d4 * 4 + u;
                float w0 = wlds[d * 192 + lane];
                float w1 = wlds[d * 192 + lane + 64];
                float w2 = wlds[d * 192 + lane + 128];
                #pragma unroll
                for (int i = 0; i < NPB; ++i) {
                    float xd = (&xv[i].x)[u];
                    acc0[i] = fmaf(xd, w0, acc0[i]);
                    acc1[i] = fmaf(xd, w1, acc1[i]);
                    acc2[i] = fmaf(xd, w2, acc2[i]);
                }
            }
        }
        #pragma unroll
        for (int i = 0; i < NPB; ++i) if (i < cnt) {
            size_t off = (size_t)(n0 + i) * DIM + lane;
            q[off] = acc0[i]; k[off] = acc1[i]; v[off] = acc2[i];
        }
    }
}

// ---------------- Kernel B: input_dot + fused edge-bucket scatter ------------
// Node phase (dense FMA) then grid-stride edge scatter; the two phases overlap
// across blocks, hiding the scatter's atomic/scattered-write latency.
__global__ __launch_bounds__(256) void vec_kernel(
    const float* __restrict__ node_vec,
    const float* __restrict__ vec_w,
    float* __restrict__ input_dot,
    const int* __restrict__ row,
    const int* __restrict__ col,
    int* __restrict__ deg,
    int2* __restrict__ perm2,
    int* __restrict__ ovcnt,
    int* __restrict__ ovlist,
    int N, int E)
{
    __shared__ float  vlds[64 * 128];          // 32 KB
    __shared__ float4 nvs[NW][NPB][3][16];     // 12 KB
    const int wave = threadIdx.x >> 6, lane = threadIdx.x & 63;

    for (int idx = threadIdx.x; idx < 64 * 128; idx += 256)
        vlds[idx] = vec_w[idx];
    __syncthreads();

    const int nstride = gridDim.x * NW * NPB;
    for (int n0 = (blockIdx.x * NW + wave) * NPB; n0 < N; n0 += nstride) {
        const int cnt = min(NPB, N - n0);
        float a0[NPB][3], a1[NPB][3];
        #pragma unroll
        for (int i = 0; i < NPB; ++i) {
            #pragma unroll
            for (int s = 0; s < 3; ++s) {
                a0[i][s] = 0.f; a1[i][s] = 0.f;
                if (i < cnt)
                    ((float*)&nvs[wave][i][s][0])[lane] =
                        node_vec[((size_t)(n0 + i) * 3 + s) * DIM + lane];
            }
        }
        #pragma unroll 2
        for (int d4 = 0; d4 < 16; ++d4) {
            #pragma unroll
            for (int u = 0; u < 4; ++u) {
                int d = d4 * 4 + u;
                float w0 = vlds[d * 128 + lane];
                float w1 = vlds[d * 128 + lane + 64];
                #pragma unroll
                for (int i = 0; i < NPB; ++i) {
                    #pragma unroll
                    for (int s = 0; s < 3; ++s) {
                        float nv = ((float*)&nvs[wave][i][s][d4])[u];
                        a0[i][s] = fmaf(nv, w0, a0[i][s]);
                        a1[i][s] = fmaf(nv, w1, a1[i][s]);
                    }
                }
            }
        }
        #pragma unroll
        for (int i = 0; i < NPB; ++i) if (i < cnt) {
            size_t off = (size_t)(n0 + i) * DIM + lane;
            input_dot[off] = a0[i][0] * a1[i][0] + a0[i][1] * a1[i][1]
                           + a0[i][2] * a1[i][2];
        }
    }

    // ---- edge scatter phase: bucket edges by destination row ----
    // Stores packed {e, col[e]} so agg_kernel needs no dependent col load.
    for (int e = blockIdx.x * 256 + threadIdx.x; e < E; e += gridDim.x * 256) {
        int r = row[e];
        int slot = atomicAdd(&deg[r], 1);
        if (slot < CAP) {
            perm2[(size_t)r * CAP + slot] = make_int2(e, col[e]);
        } else {
            int o = atomicAdd(ovcnt, 1);   // ovlist sized E: can't overflow
            ovlist[o] = e;
        }
    }
}

// ---------------- Kernel C: per-row register aggregation (no atomics) --------
// Lane j preloads edge j's {e,c,radial} coalesced; main loop gets addresses
// via __shfl so gathers for unroll-4 edges issue concurrently.
__global__ __launch_bounds__(256) void agg_kernel(
    const float* __restrict__ q,
    const float* __restrict__ k,
    const float* __restrict__ v,
    const float* __restrict__ edge_feat, // (E,64)
    const float* __restrict__ radial,
    const int2* __restrict__ perm2,
    const int* __restrict__ deg,
    float* __restrict__ m_agg,
    int N)
{
    const int wave = threadIdx.x >> 6, lane = threadIdx.x & 63;
    for (int n = blockIdx.x * NW + wave; n < N; n += gridDim.x * NW) {
        const int cn = min(deg[n], CAP);
        const int2* pr = perm2 + (size_t)n * CAP;
        int2 myec = make_int2(0, 0);
        float myrad = 0.0f;
        if (lane < cn) {
            myec = pr[lane];              // coalesced 8B
            myrad = radial[myec.x];       // 5 MB array, L2-resident
        }
        const float qd = q[(size_t)n * DIM + lane];
        float acc = 0.0f;
        #pragma unroll 4
        for (int j = 0; j < cn; ++j) {
            int   e   = __shfl(myec.x, j, 64);
            int   c   = __shfl(myec.y, j, 64);
            float rad = __shfl(myrad, j, 64);
            float kd = k[(size_t)c * DIM + lane];
            float vd = v[(size_t)c * DIM + lane];
            // edge_feat streams once (320 MB): NT keeps it out of L2 so the
            // q/k/v gather set stays cache-resident
            float ef = __builtin_nontemporal_load(&edge_feat[(size_t)e * DIM + lane]);
            float p = qd * kd;
            p += __shfl_xor(p, 1, 64);
            p += __shfl_xor(p, 2, 64);   // per-head dot in all 4 lanes
            float g = 0.5f * p * (1.0f + erff(p * 0.70710678118654752f));
            acc = fmaf(vd * ef, g * rad, acc);
        }
        // plain store: agg covers every row, ovf adds on top afterwards
        m_agg[(size_t)n * DIM + lane] = acc;
    }
}

// ---------------- Kernel O: overflow edges (deg > CAP rows; normally ~0) -----
__global__ __launch_bounds__(256) void ovf_kernel(
    const float* __restrict__ q,
    const float* __restrict__ k,
    const float* __restrict__ v,
    const float* __restrict__ edge_feat,
    const float* __restrict__ radial,
    const int* __restrict__ row,
    const int* __restrict__ col,
    const int* __restrict__ ovcnt,
    const int* __restrict__ ovlist,
    float* __restrict__ m_agg)
{
    const int wave = threadIdx.x >> 6, lane = threadIdx.x & 63;
    const int ovn = *ovcnt;
    for (int i = blockIdx.x * NW + wave; i < ovn; i += gridDim.x * NW) {
        int e = ovlist[i];
        int r = row[e], c = col[e];
        float p = q[(size_t)r * DIM + lane] * k[(size_t)c * DIM + lane];
        p += __shfl_xor(p, 1, 64);
        p += __shfl_xor(p, 2, 64);
        float g = 0.5f * p * (1.0f + erff(p * 0.70710678118654752f));
        float a = g * radial[e];
        float m = v[(size_t)c * DIM + lane] * edge_feat[(size_t)e * DIM + lane] * a;
        atomicAdd(&m_agg[(size_t)r * DIM + lane], m);
    }
}

// ---------------- Kernel D: output projection + epilogue ----------------
__global__ __launch_bounds__(256) void out_kernel(
    const float* __restrict__ m_agg,
    const float* __restrict__ input_dot,
    const float* __restrict__ out_w,   // (64,128)
    const float* __restrict__ out_b,   // (128,)
    float* __restrict__ result,        // (N,64)
    int N)
{
    __shared__ float  olds[64 * 128];      // 32 KB
    __shared__ float4 ms[NW][NPB][16];     // 4 KB
    const int wave = threadIdx.x >> 6, lane = threadIdx.x & 63;

    for (int idx = threadIdx.x; idx < 64 * 128; idx += 256)
        olds[idx] = out_w[idx];
    const float ob0 = out_b[lane], ob1 = out_b[lane + 64];
    __syncthreads();

    const int nstride = gridDim.x * NW * NPB;
    for (int n0 = (blockIdx.x * NW + wave) * NPB; n0 < N; n0 += nstride) {
        const int cnt = min(NPB, N - n0);
        float o0[NPB], o1[NPB];
        #pragma unroll
        for (int i = 0; i < NPB; ++i) {
            o0[i] = ob0; o1[i] = ob1;
            if (i < cnt)
                ((float*)&ms[wave][i][0])[lane] =
                    m_agg[(size_t)(n0 + i) * DIM + lane];
        }
        #pragma unroll 4
        for (int d4 = 0; d4 < 16; ++d4) {
            float4 mv[NPB];
            #pragma unroll
            for (int i = 0; i < NPB; ++i) mv[i] = ms[wave][i][d4];
            #pragma unroll
            for (int u = 0; u < 4; ++u) {
                int d = d4 * 4 + u;
                float w0 = olds[d * 128 + lane];
                float w1 = olds[d * 128 + lane + 64];
                #pragma unroll
                for (int i = 0; i < NPB; ++i) {
                    float md = (&mv[i].x)[u];
                    o0[i] = fmaf(md, w0, o0[i]);
                    o1[i] = fmaf(md, w1, o1[i]);
                }
            }
        }
        #pragma unroll
        for (int i = 0; i < NPB; ++i) if (i < cnt) {
            size_t off = (size_t)(n0 + i) * DIM + lane;
            result[off] = input_dot[off] * o0[i] + o1[i];
        }
    }
}

extern "C" void kernel_launch(void* const* d_in, const int* in_sizes, int n_in,
                              void* d_out, int out_size, void* d_ws, size_t ws_size,
                              hipStream_t stream)
{
    const float* node_feat = (const float*)d_in[0];
    const float* edge_feat = (const float*)d_in[1];
    const float* node_vec  = (const float*)d_in[2];
    const float* radial    = (const float*)d_in[3];
    const float* ln_g      = (const float*)d_in[4];
    const float* ln_b      = (const float*)d_in[5];
    const float* qkv_w     = (const float*)d_in[6];
    const float* qkv_b     = (const float*)d_in[7];
    const float* vec_w     = (const float*)d_in[8];
    const float* out_w     = (const float*)d_in[9];
    const float* out_b     = (const float*)d_in[10];
    const int*   row       = (const int*)d_in[11];
    const int*   col       = (const int*)d_in[12];

    const int N = in_sizes[0] / DIM;   // 50000
    const int E = in_sizes[3];         // 1250000

    float* ws    = (float*)d_ws;
    float* q     = ws;
    float* k     = q    + (size_t)N * DIM;
    float* v     = k    + (size_t)N * DIM;
    float* idot  = v    + (size_t)N * DIM;
    float* m_agg = idot + (size_t)N * DIM;
    // int section starts 64 MB in (8B-aligned)
    int2*  perm2  = (int2*)(m_agg + (size_t)N * DIM);    // N*CAP int2 = 25.6 MB
    int*   deg    = (int*)(perm2 + (size_t)N * CAP);     // N ints
    int*   ovcnt  = deg + N;
    int*   ovlist = ovcnt + 1;                           // E ints = 5 MB

    const int grid_nodes = 768;
    const int grid_agg   = (N + NW - 1) / NW;   // one wave per row

    qkv_kernel<<<grid_nodes, 256, 0, stream>>>(node_feat, ln_g, ln_b,
                                               qkv_w, qkv_b, q, k, v,
                                               deg, ovcnt, N);
    vec_kernel<<<grid_nodes, 256, 0, stream>>>(node_vec, vec_w, idot,
                                               row, col, deg, perm2,
                                               ovcnt, ovlist, N, E);
    agg_kernel<<<grid_agg, 256, 0, stream>>>(q, k, v, edge_feat, radial,
                                             perm2, deg, m_agg, N);
    ovf_kernel<<<256, 256, 0, stream>>>(q, k, v, edge_feat, radial,
                                        row, col, ovcnt, ovlist, m_agg);
    out_kernel<<<grid_nodes, 256, 0, stream>>>(m_agg, idot, out_w, out_b,
                                               (float*)d_out, N);
}